// Round 15
// baseline (48.775 us; speedup 1.0000x reference)
//
#include <hip/hip_runtime.h>
#include <hip/hip_bf16.h>

// Sinkhorn via MFMA. K = exp(-cost/100) = 1 + E, |E| <= 0.00995.
// Unnormalized chain (row scales cancel in both outputs):
//   v1 = b / S   (S = colsums(K), precomputed -- u0 = 1)
//   u1 = a / (sum_v1 + E v1 + eps)
//   v2 = b / (sum_u1 + E^T u1)
//   u2 = a / (sum_v2 + E v2 + eps);  T = KM v2 (KM single-bf16)
//   wnorm = mean sum u2*(T+eps);  grad = centered log(u2) * lam/B
//
// r15 = r11 (44.7us verified: 8-wave blocks, 16 rows/wave, 2 blocks/CU,
// SGB {2ds,1mfma} pin, pre-swizzled tables, S-table, single-bf16 KM,
// LDS-transpose grad stores, separate sink_reduce) + ONE salvaged r13
// component: KM loaded to regs in the prologue (latency hidden) and
// ds_written into EA (dead after v2) before the u2 phase -> the serial
// KM-restage L2 stall between barriers is gone. r13's other two components
// (agent-scope atomic fold, SGB {8,4}) are confirmed regressions, excluded.
// r14 (4-wave/32-row) and r12 (resident tables, 1 blk/CU) were neutral/worse.

typedef __attribute__((ext_vector_type(4))) float f32x4;
typedef __attribute__((ext_vector_type(4))) short s16x4;
typedef __attribute__((ext_vector_type(8))) short s16x8;

constexpr int   BLOCK = 512;               // 8 waves, 16 rows each
constexpr float EPSF  = 1e-8f;
constexpr float LOG2E = 1.44269504088896340736f;
constexpr float LN2   = 0.69314718055994530942f;
constexpr float GRADS = LN2 * 100.0f / 65536.0f;   // ln2 * lam / B

// d_ws layout: halfwords [0:16K) E, [16K:32K) E^T, [32K:48K) KM (swizzled);
// floats: S at f-off 24576 (128), partials at 24704 (512).

#define SGB_PAIR() do {                                      \
    __builtin_amdgcn_sched_group_barrier(0x100, 2, 0);       \
    __builtin_amdgcn_sched_group_barrier(0x008, 1, 0);       \
  } while (0)

__device__ __forceinline__ unsigned short f2bf(float x) {
  unsigned u = __builtin_bit_cast(unsigned, x);
  u += 0x7fffu + ((u >> 16) & 1u);
  return (unsigned short)(u >> 16);
}
__device__ __forceinline__ float bf2f(short h) {
  return __builtin_bit_cast(float, (unsigned)(unsigned short)h << 16);
}
__device__ __forceinline__ short f2bf_hot(float x) {
  return __builtin_bit_cast(short, __float2bfloat16(x));
}

__device__ __forceinline__ int swzw(int r, int c) {
  return (r << 7) + ((((c >> 2) ^ ((r & 7) << 2)) << 2) | (c & 3));
}

__device__ __forceinline__ s16x8 afrag(const short* M, int row, int kb, int h) {
  const int base = (row << 7) + ((((kb >> 2) + h) ^ ((row & 7) << 2)) << 2);
  const s16x4 lo = *reinterpret_cast<const s16x4*>(M + base);
  const s16x4 hi = *reinterpret_cast<const s16x4*>(M + (base ^ 16));
  s16x8 r;
  r[0] = lo[0]; r[1] = lo[1]; r[2] = lo[2]; r[3] = lo[3];
  r[4] = hi[0]; r[5] = hi[1]; r[6] = hi[2]; r[7] = hi[3];
  return r;
}

__device__ __forceinline__ s16x8 packb(const f32x4 a, const f32x4 b) {
  s16x8 r;
  r[0] = f2bf_hot(a[0]); r[1] = f2bf_hot(a[1]);
  r[2] = f2bf_hot(a[2]); r[3] = f2bf_hot(a[3]);
  r[4] = f2bf_hot(b[0]); r[5] = f2bf_hot(b[1]);
  r[6] = f2bf_hot(b[2]); r[7] = f2bf_hot(b[3]);
  return r;
}

// ---- one-shot precompute: E, E^T, KM (swizzled bf16) + S = colsums(K) ----
__global__ __launch_bounds__(256)
void sink_pre(const float* __restrict__ cost, unsigned short* __restrict__ wh,
              float* __restrict__ Sf)
{
  const float c1 = LOG2E * 0.01f;
  const int tid = threadIdx.x;
  if (blockIdx.x < 32) {
    for (int idx = blockIdx.x * 256 + tid; idx < 16384; idx += 8192) {
      const int r = idx >> 7, c = idx & 127;
      const float cst = cost[idx];
      const float k   = __builtin_amdgcn_exp2f(-cst * c1);
      const unsigned short eb = f2bf(k - 1.0f);
      wh[swzw(r, c)]          = eb;             // E
      wh[16384 + swzw(c, r)]  = eb;             // E^T
      wh[32768 + swzw(r, c)]  = f2bf(cst * k);  // KM
    }
  } else {
    __shared__ float ps[256];
    const int i = tid & 127, jh = tid >> 7;
    float s = 0.f;
#pragma unroll 8
    for (int j = jh * 64; j < jh * 64 + 64; ++j)
      s += __builtin_amdgcn_exp2f(-cost[(j << 7) + i] * c1);
    ps[tid] = s;
    __syncthreads();
    if (tid < 128) Sf[tid] = ps[tid] + ps[tid + 128];
  }
}

__global__ __launch_bounds__(BLOCK, 4)
void sink_mfma(const float* __restrict__ pred,
               const float* __restrict__ tgt,
               const unsigned short* __restrict__ wh,
               const float* __restrict__ Sf,
               float* __restrict__ out,
               float* __restrict__ wsf)
{
  __shared__ __align__(16) short EA[128 * 128];   // E^T -> KM -> grad transpose
  __shared__ __align__(16) short EB[128 * 128];   // E
  __shared__ float wred[8];

  const int tid  = threadIdx.x;
  const int lane = tid & 63;
  const int wv   = tid >> 6;
  const int cl   = lane & 15;
  const int h    = lane >> 4;

  const int row0 = (blockIdx.x << 7) + (wv << 4);
  const int rr   = (row0 + cl) << 7;

  // ---- inputs + KM regs first (HBM/L2 latency overlaps staging below)
  float4 p4[8], t4[8], s4[8];
  uint4 kmr[4];
#pragma unroll
  for (int mt = 0; mt < 8; ++mt) {
    p4[mt] = *reinterpret_cast<const float4*>(&pred[rr + (mt << 4) + (h << 2)]);
    t4[mt] = *reinterpret_cast<const float4*>(&tgt [rr + (mt << 4) + (h << 2)]);
    s4[mt] = *reinterpret_cast<const float4*>(&Sf[(mt << 4) + (h << 2)]);
  }
  {
    const uint4* gK = reinterpret_cast<const uint4*>(wh + 32768);
#pragma unroll
    for (int k = 0; k < 4; ++k) kmr[k] = gK[tid + k * BLOCK];
  }

  // ---- stage E / E^T (pre-swizzled, pure coalesced copies)
  {
    const uint4* gB = reinterpret_cast<const uint4*>(wh);
    const uint4* gA = reinterpret_cast<const uint4*>(wh + 16384);
    uint4* lB = reinterpret_cast<uint4*>(EB);
    uint4* lA = reinterpret_cast<uint4*>(EA);
#pragma unroll
    for (int k = 0; k < 4; ++k) {
      lB[tid + k * BLOCK] = gB[tid + k * BLOCK];
      lA[tid + k * BLOCK] = gA[tid + k * BLOCK];
    }
  }

  // ---- pack a,b; v1 = b / S elementwise; sum_v1
  s16x8 ab[4], bb[4], vf[4], uf[4];
  f32x4 X[8];
  float sum_v = 0.f;
#pragma unroll
  for (int mt = 0; mt < 8; ++mt) {
    f32x4 qa, qb, v;
    qa[0] = p4[mt].x + EPSF; qa[1] = p4[mt].y + EPSF;
    qa[2] = p4[mt].z + EPSF; qa[3] = p4[mt].w + EPSF;
    qb[0] = t4[mt].x + EPSF; qb[1] = t4[mt].y + EPSF;
    qb[2] = t4[mt].z + EPSF; qb[3] = t4[mt].w + EPSF;
    v[0] = qb[0] * __builtin_amdgcn_rcpf(s4[mt].x);
    v[1] = qb[1] * __builtin_amdgcn_rcpf(s4[mt].y);
    v[2] = qb[2] * __builtin_amdgcn_rcpf(s4[mt].z);
    v[3] = qb[3] * __builtin_amdgcn_rcpf(s4[mt].w);
    sum_v += v[0] + v[1] + v[2] + v[3];
    X[mt] = v;
#pragma unroll
    for (int q = 0; q < 4; ++q) {
      ab[mt >> 1][(mt & 1) * 4 + q] = f2bf_hot(qa[q]);
      bb[mt >> 1][(mt & 1) * 4 + q] = f2bf_hot(qb[q]);
    }
  }
#pragma unroll
  for (int s = 0; s < 4; ++s) vf[s] = packb(X[2 * s], X[2 * s + 1]);
  sum_v += __shfl_xor(sum_v, 16);
  sum_v += __shfl_xor(sum_v, 32);
  __syncthreads();

  // ======== u1 = a / (sum_v1 + E v1 + eps)  [EB] ========
#pragma unroll
  for (int mt = 0; mt < 8; ++mt) X[mt] = f32x4{0, 0, 0, 0};
#pragma unroll
  for (int s = 0; s < 4; ++s)
#pragma unroll
    for (int mt = 0; mt < 8; ++mt) {
      X[mt] = __builtin_amdgcn_mfma_f32_16x16x32_bf16(
          afrag(EB, cl + (mt << 4), s << 5, h), vf[s], X[mt], 0, 0, 0);
      SGB_PAIR();
    }
  float sum_u = 0.f;
#pragma unroll
  for (int mt = 0; mt < 8; ++mt)
#pragma unroll
    for (int q = 0; q < 4; ++q) {
      const float a = bf2f(ab[mt >> 1][(mt & 1) * 4 + q]);
      const float r = a * __builtin_amdgcn_rcpf(sum_v + X[mt][q] + EPSF);
      X[mt][q] = r;
      sum_u += r;
    }
#pragma unroll
  for (int s = 0; s < 4; ++s) uf[s] = packb(X[2 * s], X[2 * s + 1]);
  sum_u += __shfl_xor(sum_u, 16);
  sum_u += __shfl_xor(sum_u, 32);

  // ======== v2 = b / (sum_u1 + E^T u1)  [EA] ========
#pragma unroll
  for (int mt = 0; mt < 8; ++mt) X[mt] = f32x4{0, 0, 0, 0};
#pragma unroll
  for (int s = 0; s < 4; ++s)
#pragma unroll
    for (int mt = 0; mt < 8; ++mt) {
      X[mt] = __builtin_amdgcn_mfma_f32_16x16x32_bf16(
          afrag(EA, cl + (mt << 4), s << 5, h), uf[s], X[mt], 0, 0, 0);
      SGB_PAIR();
    }
  sum_v = 0.f;
#pragma unroll
  for (int mt = 0; mt < 8; ++mt)
#pragma unroll
    for (int q = 0; q < 4; ++q) {
      const float b = bf2f(bb[mt >> 1][(mt & 1) * 4 + q]);
      const float v = b * __builtin_amdgcn_rcpf(sum_u + X[mt][q]);
      X[mt][q] = v;
      sum_v += v;
    }
#pragma unroll
  for (int s = 0; s < 4; ++s) vf[s] = packb(X[2 * s], X[2 * s + 1]);
  sum_v += __shfl_xor(sum_v, 16);
  sum_v += __shfl_xor(sum_v, 32);

  // ---- E^T dead: write KM (in regs since prologue) into EA; overlaps u2
  __syncthreads();
  {
    uint4* lA = reinterpret_cast<uint4*>(EA);
#pragma unroll
    for (int k = 0; k < 4; ++k) lA[tid + k * BLOCK] = kmr[k];
  }

  // ======== u2 = a / (sum_v2 + E v2 + eps)  [EB] ========
#pragma unroll
  for (int mt = 0; mt < 8; ++mt) X[mt] = f32x4{0, 0, 0, 0};
#pragma unroll
  for (int s = 0; s < 4; ++s)
#pragma unroll
    for (int mt = 0; mt < 8; ++mt) {
      X[mt] = __builtin_amdgcn_mfma_f32_16x16x32_bf16(
          afrag(EB, cl + (mt << 4), s << 5, h), vf[s], X[mt], 0, 0, 0);
      SGB_PAIR();
    }
#pragma unroll
  for (int mt = 0; mt < 8; ++mt)
#pragma unroll
    for (int q = 0; q < 4; ++q) {
      const float a = bf2f(ab[mt >> 1][(mt & 1) * 4 + q]);
      X[mt][q] = a * __builtin_amdgcn_rcpf(sum_v + X[mt][q] + EPSF);  // u2
    }
  __syncthreads();   // KM writes complete block-wide; EA = KM

  // ======== T = KM v2  [EA] ========
  f32x4 T[8];
#pragma unroll
  for (int mt = 0; mt < 8; ++mt) T[mt] = f32x4{0, 0, 0, 0};
#pragma unroll
  for (int s = 0; s < 4; ++s)
#pragma unroll
    for (int mt = 0; mt < 8; ++mt) {
      T[mt] = __builtin_amdgcn_mfma_f32_16x16x32_bf16(
          afrag(EA, cl + (mt << 4), s << 5, h), vf[s], T[mt], 0, 0, 0);
      SGB_PAIR();
    }

  // wnorm partial: sum u2*(T+eps)
  float wsum = 0.f;
#pragma unroll
  for (int mt = 0; mt < 8; ++mt)
#pragma unroll
    for (int q = 0; q < 4; ++q)
      wsum += X[mt][q] * (T[mt][q] + EPSF);
  wsum += __shfl_xor(wsum, 1);
  wsum += __shfl_xor(wsum, 2);
  wsum += __shfl_xor(wsum, 4);
  wsum += __shfl_xor(wsum, 8);
  wsum += __shfl_xor(wsum, 16);
  wsum += __shfl_xor(wsum, 32);
  if (lane == 0) wred[wv] = wsum;

  // grad = (log2(u2) - rowmean) * ln2*lam/B, coalesced via EA transpose
  {
#pragma unroll
    for (int mt = 0; mt < 8; ++mt)
#pragma unroll
      for (int q = 0; q < 4; ++q)
        X[mt][q] = __builtin_amdgcn_logf(X[mt][q]);
    float sm = 0.f;
#pragma unroll
    for (int mt = 0; mt < 8; ++mt)
#pragma unroll
      for (int q = 0; q < 4; ++q) sm += X[mt][q];
    sm += __shfl_xor(sm, 16);
    sm += __shfl_xor(sm, 32);
    const float mean = sm * 0.0078125f;

    float* TAf = reinterpret_cast<float*>(EA);   // 8192 floats = 64 rows
    const int obase = 1 + (blockIdx.x << 14);
    const int lrow  = (wv & 3) << 4;
#pragma unroll
    for (int half = 0; half < 2; ++half) {
      __syncthreads();
      if ((wv >> 2) == half) {
#pragma unroll
        for (int mt = 0; mt < 8; ++mt)
#pragma unroll
          for (int q = 0; q < 4; ++q) {
            const int col = (mt << 4) + (h << 2) + q;
            TAf[((lrow + cl) << 7) + (col ^ ((cl & 7) << 2))] =
                (X[mt][q] - mean) * GRADS;
          }
      }
      __syncthreads();
#pragma unroll
      for (int k = 0; k < 16; ++k) {
        const int lin = k * BLOCK + tid;
        const int row = lin >> 7, col = lin & 127;
        out[obase + (half << 13) + lin] =
            TAf[(row << 7) + (col ^ ((row & 7) << 2))];
      }
    }
  }

  __syncthreads();
  if (tid == 0) {
    float s = 0.f;
#pragma unroll
    for (int w = 0; w < 8; ++w) s += wred[w];
    wsf[blockIdx.x] = s;
  }
}

__global__ void sink_reduce(const float* __restrict__ wsf, float* __restrict__ out)
{
  float s = 0.f;
  for (int i = threadIdx.x; i < 512; i += 256) s += wsf[i];
  s += __shfl_xor(s, 1);
  s += __shfl_xor(s, 2);
  s += __shfl_xor(s, 4);
  s += __shfl_xor(s, 8);
  s += __shfl_xor(s, 16);
  s += __shfl_xor(s, 32);
  __shared__ float sm[4];
  if ((threadIdx.x & 63) == 0) sm[threadIdx.x >> 6] = s;
  __syncthreads();
  if (threadIdx.x == 0) out[0] = (sm[0] + sm[1] + sm[2] + sm[3]) * (1.0f / 65536.0f);
}

extern "C" void kernel_launch(void* const* d_in, const int* in_sizes, int n_in,
                              void* d_out, int out_size, void* d_ws, size_t ws_size,
                              hipStream_t stream)
{
  const float* pred = (const float*)d_in[0];
  const float* tgt  = (const float*)d_in[1];
  const float* cost = (const float*)d_in[2];
  float* out = (float*)d_out;
  unsigned short* wh = (unsigned short*)d_ws;       // 96 KB tables
  float* Sf  = ((float*)d_ws) + 24576;              // 128 colsums
  float* wsf = ((float*)d_ws) + 24704;              // 512 block partials

  sink_pre<<<33, 256, 0, stream>>>(cost, wh, Sf);
  sink_mfma<<<512, BLOCK, 0, stream>>>(pred, tgt, wh, Sf, out, wsf);
  sink_reduce<<<1, 256, 0, stream>>>(wsf, out);
}

// Round 16
// 44.808 us; speedup vs baseline: 1.0885x; 1.0885x over previous
//
#include <hip/hip_runtime.h>
#include <hip/hip_bf16.h>

// Sinkhorn via MFMA. K = exp(-cost/100) = 1 + E, |E| <= 0.00995.
// Unnormalized chain (row scales cancel in both outputs):
//   v1 = b / S          (S = K^T 1, precomputed column sums -- u0=1!)
//   u1 = a / (K v1)     (MV2: E x V^T)
//   v2 = b / (K^T u1)   (MV1: E^T x U^T)
//   u2 = a / (K v2)     (MV2)
//   wnorm = mean sum u2*(KM v2 + eps);  grad = centered log(u2) * lam/B
// Birkhoff contraction tanh(0.02/4)~0.005/half-step => v2 shape error ~5e-6,
// same fixed point as reference's early-stopped 50-iter loop.
//
// FINAL (r16 = r11 verbatim, the verified 44.7us optimum). Session ledger:
//   r8  sched_group_barrier {2ds,1mfma} pin -> killed 200-800MB scratch spill
//   r10 tables precomputed pre-swizzled in d_ws; NITER=2; cvt_pk packs
//   r11 S-table for first matvec; single-bf16 KM; LDS-transpose grad stores
//   r12 resident-KM/1-blk-per-CU: REGRESSED (lost 2-blk overlap, VGPR cap)
//   r13 folded atomic reduce + deep SGB: REGRESSED (L2 writebacks, conflicts)
//   r14 4-wave/32-row blocks: neutral (LDS traffic halved, occupancy halved)
//   r15 KM early-load: neutral-negative (prologue FETCH/WRITE grew)
// Remaining time is distributed: no pipe >25% busy; serialization-structural
// plateau, not a classical roofline.

typedef __attribute__((ext_vector_type(4))) float f32x4;
typedef __attribute__((ext_vector_type(4))) short s16x4;
typedef __attribute__((ext_vector_type(8))) short s16x8;

constexpr int   BLOCK = 512;               // 8 waves, 16 rows each
constexpr float EPSF  = 1e-8f;
constexpr float LOG2E = 1.44269504088896340736f;
constexpr float LN2   = 0.69314718055994530942f;
constexpr float GRADS = LN2 * 100.0f / 65536.0f;   // ln2 * lam / B

// d_ws layout: halfwords [0:16K) E, [16K:32K) E^T, [32K:48K) KM (swizzled);
// floats: S at f-off 24576 (128), partials at 24704 (512).

#define SGB_PAIR() do {                                      \
    __builtin_amdgcn_sched_group_barrier(0x100, 2, 0);       \
    __builtin_amdgcn_sched_group_barrier(0x008, 1, 0);       \
  } while (0)

__device__ __forceinline__ unsigned short f2bf(float x) {
  unsigned u = __builtin_bit_cast(unsigned, x);
  u += 0x7fffu + ((u >> 16) & 1u);
  return (unsigned short)(u >> 16);
}
__device__ __forceinline__ float bf2f(short h) {
  return __builtin_bit_cast(float, (unsigned)(unsigned short)h << 16);
}
__device__ __forceinline__ short f2bf_hot(float x) {
  return __builtin_bit_cast(short, __float2bfloat16(x));
}

__device__ __forceinline__ int swzw(int r, int c) {
  return (r << 7) + ((((c >> 2) ^ ((r & 7) << 2)) << 2) | (c & 3));
}

__device__ __forceinline__ s16x8 afrag(const short* M, int row, int kb, int h) {
  const int base = (row << 7) + ((((kb >> 2) + h) ^ ((row & 7) << 2)) << 2);
  const s16x4 lo = *reinterpret_cast<const s16x4*>(M + base);
  const s16x4 hi = *reinterpret_cast<const s16x4*>(M + (base ^ 16));
  s16x8 r;
  r[0] = lo[0]; r[1] = lo[1]; r[2] = lo[2]; r[3] = lo[3];
  r[4] = hi[0]; r[5] = hi[1]; r[6] = hi[2]; r[7] = hi[3];
  return r;
}

__device__ __forceinline__ s16x8 packb(const f32x4 a, const f32x4 b) {
  s16x8 r;
  r[0] = f2bf_hot(a[0]); r[1] = f2bf_hot(a[1]);
  r[2] = f2bf_hot(a[2]); r[3] = f2bf_hot(a[3]);
  r[4] = f2bf_hot(b[0]); r[5] = f2bf_hot(b[1]);
  r[6] = f2bf_hot(b[2]); r[7] = f2bf_hot(b[3]);
  return r;
}

// ---- one-shot precompute: E, E^T, KM (swizzled bf16) + S = colsums(K) ----
__global__ __launch_bounds__(256)
void sink_pre(const float* __restrict__ cost, unsigned short* __restrict__ wh,
              float* __restrict__ Sf)
{
  const float c1 = LOG2E * 0.01f;
  const int tid = threadIdx.x;
  if (blockIdx.x < 32) {
    for (int idx = blockIdx.x * 256 + tid; idx < 16384; idx += 8192) {
      const int r = idx >> 7, c = idx & 127;
      const float cst = cost[idx];
      const float k   = __builtin_amdgcn_exp2f(-cst * c1);
      const unsigned short eb = f2bf(k - 1.0f);
      wh[swzw(r, c)]          = eb;             // E
      wh[16384 + swzw(c, r)]  = eb;             // E^T
      wh[32768 + swzw(r, c)]  = f2bf(cst * k);  // KM (single bf16)
    }
  } else {
    __shared__ float ps[256];
    const int i = tid & 127, jh = tid >> 7;
    float s = 0.f;
#pragma unroll 8
    for (int j = jh * 64; j < jh * 64 + 64; ++j)
      s += __builtin_amdgcn_exp2f(-cost[(j << 7) + i] * c1);
    ps[tid] = s;
    __syncthreads();
    if (tid < 128) Sf[tid] = ps[tid] + ps[tid + 128];
  }
}

__global__ __launch_bounds__(BLOCK, 4)
void sink_mfma(const float* __restrict__ pred,
               const float* __restrict__ tgt,
               const unsigned short* __restrict__ wh,
               const float* __restrict__ Sf,
               float* __restrict__ out,
               float* __restrict__ wsf)
{
  __shared__ __align__(16) short EA[128 * 128];   // E^T; later grad-transpose
  __shared__ __align__(16) short EB[128 * 128];   // E; later KM
  __shared__ float wred[8];

  const int tid  = threadIdx.x;
  const int lane = tid & 63;
  const int wv   = tid >> 6;
  const int cl   = lane & 15;
  const int h    = lane >> 4;

  const int row0 = (blockIdx.x << 7) + (wv << 4);
  const int rr   = (row0 + cl) << 7;

  // ---- inputs first (HBM latency overlaps staging below)
  float4 p4[8], t4[8], s4[8];
#pragma unroll
  for (int mt = 0; mt < 8; ++mt) {
    p4[mt] = *reinterpret_cast<const float4*>(&pred[rr + (mt << 4) + (h << 2)]);
    t4[mt] = *reinterpret_cast<const float4*>(&tgt [rr + (mt << 4) + (h << 2)]);
    s4[mt] = *reinterpret_cast<const float4*>(&Sf[(mt << 4) + (h << 2)]);
  }

  // ---- stage E / E^T (pre-swizzled, pure coalesced copies)
  {
    const uint4* gB = reinterpret_cast<const uint4*>(wh);
    const uint4* gA = reinterpret_cast<const uint4*>(wh + 16384);
    uint4* lB = reinterpret_cast<uint4*>(EB);
    uint4* lA = reinterpret_cast<uint4*>(EA);
#pragma unroll
    for (int k = 0; k < 4; ++k) {
      lB[tid + k * BLOCK] = gB[tid + k * BLOCK];
      lA[tid + k * BLOCK] = gA[tid + k * BLOCK];
    }
  }

  // ---- pack a,b; v1 = b / S elementwise; sum_v1
  s16x8 ab[4], bb[4], vf[4], uf[4];
  f32x4 X[8];
  float sum_v = 0.f;
#pragma unroll
  for (int mt = 0; mt < 8; ++mt) {
    f32x4 qa, qb, v;
    qa[0] = p4[mt].x + EPSF; qa[1] = p4[mt].y + EPSF;
    qa[2] = p4[mt].z + EPSF; qa[3] = p4[mt].w + EPSF;
    qb[0] = t4[mt].x + EPSF; qb[1] = t4[mt].y + EPSF;
    qb[2] = t4[mt].z + EPSF; qb[3] = t4[mt].w + EPSF;
    v[0] = qb[0] * __builtin_amdgcn_rcpf(s4[mt].x);
    v[1] = qb[1] * __builtin_amdgcn_rcpf(s4[mt].y);
    v[2] = qb[2] * __builtin_amdgcn_rcpf(s4[mt].z);
    v[3] = qb[3] * __builtin_amdgcn_rcpf(s4[mt].w);
    sum_v += v[0] + v[1] + v[2] + v[3];
    X[mt] = v;
#pragma unroll
    for (int q = 0; q < 4; ++q) {
      ab[mt >> 1][(mt & 1) * 4 + q] = f2bf_hot(qa[q]);
      bb[mt >> 1][(mt & 1) * 4 + q] = f2bf_hot(qb[q]);
    }
  }
#pragma unroll
  for (int s = 0; s < 4; ++s) vf[s] = packb(X[2 * s], X[2 * s + 1]);
  sum_v += __shfl_xor(sum_v, 16);
  sum_v += __shfl_xor(sum_v, 32);
  __syncthreads();

  // ======== u1 = a / (sum_v1 + E v1 + eps)  [MV2 on EB] ========
#pragma unroll
  for (int mt = 0; mt < 8; ++mt) X[mt] = f32x4{0, 0, 0, 0};
#pragma unroll
  for (int s = 0; s < 4; ++s)
#pragma unroll
    for (int mt = 0; mt < 8; ++mt) {
      X[mt] = __builtin_amdgcn_mfma_f32_16x16x32_bf16(
          afrag(EB, cl + (mt << 4), s << 5, h), vf[s], X[mt], 0, 0, 0);
      SGB_PAIR();
    }
  float sum_u = 0.f;
#pragma unroll
  for (int mt = 0; mt < 8; ++mt)
#pragma unroll
    for (int q = 0; q < 4; ++q) {
      const float a = bf2f(ab[mt >> 1][(mt & 1) * 4 + q]);
      const float r = a * __builtin_amdgcn_rcpf(sum_v + X[mt][q] + EPSF);
      X[mt][q] = r;
      sum_u += r;
    }
#pragma unroll
  for (int s = 0; s < 4; ++s) uf[s] = packb(X[2 * s], X[2 * s + 1]);
  sum_u += __shfl_xor(sum_u, 16);
  sum_u += __shfl_xor(sum_u, 32);

  // ======== v2 = b / (sum_u1 + E^T u1)  [MV1 on EA] ========
#pragma unroll
  for (int mt = 0; mt < 8; ++mt) X[mt] = f32x4{0, 0, 0, 0};
#pragma unroll
  for (int s = 0; s < 4; ++s)
#pragma unroll
    for (int mt = 0; mt < 8; ++mt) {
      X[mt] = __builtin_amdgcn_mfma_f32_16x16x32_bf16(
          afrag(EA, cl + (mt << 4), s << 5, h), uf[s], X[mt], 0, 0, 0);
      SGB_PAIR();
    }
  sum_v = 0.f;
#pragma unroll
  for (int mt = 0; mt < 8; ++mt)
#pragma unroll
    for (int q = 0; q < 4; ++q) {
      const float b = bf2f(bb[mt >> 1][(mt & 1) * 4 + q]);
      const float v = b * __builtin_amdgcn_rcpf(sum_u + X[mt][q]);
      X[mt][q] = v;
      sum_v += v;
    }
#pragma unroll
  for (int s = 0; s < 4; ++s) vf[s] = packb(X[2 * s], X[2 * s + 1]);
  sum_v += __shfl_xor(sum_v, 16);
  sum_v += __shfl_xor(sum_v, 32);

  // ======== u2 = a / (sum_v2 + E v2 + eps)  [MV2 on EB] ========
#pragma unroll
  for (int mt = 0; mt < 8; ++mt) X[mt] = f32x4{0, 0, 0, 0};
#pragma unroll
  for (int s = 0; s < 4; ++s)
#pragma unroll
    for (int mt = 0; mt < 8; ++mt) {
      X[mt] = __builtin_amdgcn_mfma_f32_16x16x32_bf16(
          afrag(EB, cl + (mt << 4), s << 5, h), vf[s], X[mt], 0, 0, 0);
      SGB_PAIR();
    }
#pragma unroll
  for (int mt = 0; mt < 8; ++mt)
#pragma unroll
    for (int q = 0; q < 4; ++q) {
      const float a = bf2f(ab[mt >> 1][(mt & 1) * 4 + q]);
      X[mt][q] = a * __builtin_amdgcn_rcpf(sum_v + X[mt][q] + EPSF);  // u2
    }

  // ======== T = KM v2  [restage KM into EB] ========
  __syncthreads();
  {
    const uint4* gK = reinterpret_cast<const uint4*>(wh + 32768);
    uint4* lB = reinterpret_cast<uint4*>(EB);
#pragma unroll
    for (int k = 0; k < 4; ++k) lB[tid + k * BLOCK] = gK[tid + k * BLOCK];
  }
  __syncthreads();

  f32x4 T[8];
#pragma unroll
  for (int mt = 0; mt < 8; ++mt) T[mt] = f32x4{0, 0, 0, 0};
#pragma unroll
  for (int s = 0; s < 4; ++s)
#pragma unroll
    for (int mt = 0; mt < 8; ++mt) {
      T[mt] = __builtin_amdgcn_mfma_f32_16x16x32_bf16(
          afrag(EB, cl + (mt << 4), s << 5, h), vf[s], T[mt], 0, 0, 0);
      SGB_PAIR();
    }

  // wnorm partial: sum u2*(T+eps)
  float wsum = 0.f;
#pragma unroll
  for (int mt = 0; mt < 8; ++mt)
#pragma unroll
    for (int q = 0; q < 4; ++q)
      wsum += X[mt][q] * (T[mt][q] + EPSF);
  wsum += __shfl_xor(wsum, 1);
  wsum += __shfl_xor(wsum, 2);
  wsum += __shfl_xor(wsum, 4);
  wsum += __shfl_xor(wsum, 8);
  wsum += __shfl_xor(wsum, 16);
  wsum += __shfl_xor(wsum, 32);
  if (lane == 0) wred[wv] = wsum;

  // grad = (log2(u2) - rowmean) * ln2*lam/B, written coalesced via EA transpose
  {
#pragma unroll
    for (int mt = 0; mt < 8; ++mt)
#pragma unroll
      for (int q = 0; q < 4; ++q)
        X[mt][q] = __builtin_amdgcn_logf(X[mt][q]);
    float sm = 0.f;
#pragma unroll
    for (int mt = 0; mt < 8; ++mt)
#pragma unroll
      for (int q = 0; q < 4; ++q) sm += X[mt][q];
    sm += __shfl_xor(sm, 16);
    sm += __shfl_xor(sm, 32);
    const float mean = sm * 0.0078125f;

    float* TAf = reinterpret_cast<float*>(EA);   // 8192 floats = 64 rows
    const int obase = 1 + (blockIdx.x << 14);
    const int lrow  = (wv & 3) << 4;             // row-in-half for this wave
#pragma unroll
    for (int half = 0; half < 2; ++half) {
      __syncthreads();
      if ((wv >> 2) == half) {
#pragma unroll
        for (int mt = 0; mt < 8; ++mt)
#pragma unroll
          for (int q = 0; q < 4; ++q) {
            const int col = (mt << 4) + (h << 2) + q;
            TAf[((lrow + cl) << 7) + (col ^ ((cl & 7) << 2))] =
                (X[mt][q] - mean) * GRADS;
          }
      }
      __syncthreads();
#pragma unroll
      for (int k = 0; k < 16; ++k) {
        const int lin = k * BLOCK + tid;
        const int row = lin >> 7, col = lin & 127;
        out[obase + (half << 13) + lin] =
            TAf[(row << 7) + (col ^ ((row & 7) << 2))];
      }
    }
  }

  __syncthreads();
  if (tid == 0) {
    float s = 0.f;
#pragma unroll
    for (int w = 0; w < 8; ++w) s += wred[w];
    wsf[blockIdx.x] = s;
  }
}

__global__ void sink_reduce(const float* __restrict__ wsf, float* __restrict__ out)
{
  float s = 0.f;
  for (int i = threadIdx.x; i < 512; i += 256) s += wsf[i];
  s += __shfl_xor(s, 1);
  s += __shfl_xor(s, 2);
  s += __shfl_xor(s, 4);
  s += __shfl_xor(s, 8);
  s += __shfl_xor(s, 16);
  s += __shfl_xor(s, 32);
  __shared__ float sm[4];
  if ((threadIdx.x & 63) == 0) sm[threadIdx.x >> 6] = s;
  __syncthreads();
  if (threadIdx.x == 0) out[0] = (sm[0] + sm[1] + sm[2] + sm[3]) * (1.0f / 65536.0f);
}

extern "C" void kernel_launch(void* const* d_in, const int* in_sizes, int n_in,
                              void* d_out, int out_size, void* d_ws, size_t ws_size,
                              hipStream_t stream)
{
  const float* pred = (const float*)d_in[0];
  const float* tgt  = (const float*)d_in[1];
  const float* cost = (const float*)d_in[2];
  float* out = (float*)d_out;
  unsigned short* wh = (unsigned short*)d_ws;       // 96 KB tables
  float* Sf  = ((float*)d_ws) + 24576;              // 128 colsums
  float* wsf = ((float*)d_ws) + 24704;              // 512 block partials

  sink_pre<<<33, 256, 0, stream>>>(cost, wh, Sf);
  sink_mfma<<<512, BLOCK, 0, stream>>>(pred, tgt, wh, Sf, out, wsf);
  sink_reduce<<<1, 256, 0, stream>>>(wsf, out);
}